// Round 3
// baseline (233.456 us; speedup 1.0000x reference)
//
#include <hip/hip_runtime.h>
#include <hip/hip_bf16.h>
#include <math.h>

#define N_NODES 4096
#define F_INN   256
#define F_OUTT  64
#define HID     64
#define MAXDEG  64

typedef __attribute__((ext_vector_type(8))) short bf16x8;
typedef __attribute__((ext_vector_type(4))) float f32x4;

// Scratch in device globals (no ws_size dependence). Fully rewritten each call.
__device__ int    g_mode;                    // 0 = fp32 inputs, 1 = bf16 inputs
__device__ int    g_anyArr[64];              // per-block detector flags
__device__ float  g_Wh [N_NODES * F_OUTT];
__device__ float  g_s1 [N_NODES];
__device__ float  g_s2 [N_NODES];
__device__ int    g_rev[N_NODES * MAXDEG];
__device__ int    g_perm[N_NODES];
__device__ float4 g_GX [N_NODES * F_OUTT];   // per (node, unit): quad {i,f,g,o} + bias

__device__ __forceinline__ float bf2f(unsigned short u) {
  union { unsigned int i; float f; } v; v.i = ((unsigned int)u) << 16; return v.f;
}
__device__ __forceinline__ unsigned short f2bf(float f) {   // RNE
  union { __hip_bfloat16 b; unsigned short u; } v; v.b = __float2bfloat16(f); return v.u;
}

__device__ __forceinline__ float bcastf(float v, int l) {
  return __int_as_float(__builtin_amdgcn_readlane(__float_as_int(v), l));
}

// r13: raw v_rcp_f32 (1 inst, ~1e-7 rel err) instead of fp32 '/' (no
// fast-math -> IEEE div expansion of ~8-10 insts). Proven: 245 -> 227us.
__device__ __forceinline__ float rcp_fast(float x) { return __builtin_amdgcn_rcpf(x); }

__device__ __forceinline__ float sigm(float x) {
  return rcp_fast(1.f + __expf(-x));                   // mul,exp,add,rcp
}
__device__ __forceinline__ float tanh_fast(float x) {
  return fmaf(-2.f, rcp_fast(1.f + __expf(2.f * x)), 1.f);  // mul,exp,add,rcp,fma
}

// count of set bits in mask among lanes strictly below mine
__device__ __forceinline__ int mbcnt64(unsigned long long m) {
  return __builtin_amdgcn_mbcnt_hi((unsigned)(m >> 32),
         __builtin_amdgcn_mbcnt_lo((unsigned)(m & 0xFFFFFFFFull), 0));
}

__device__ __forceinline__ bf16x8 zfrag() {
  bf16x8 z;
  #pragma unroll
  for (int i = 0; i < 8; i++) z[i] = 0;
  return z;
}

// Lightweight block barrier for LDS-only exchange (r10-validated): orders ds
// ops but does not force a vmcnt drain of in-flight global prefetches.
__device__ __forceinline__ void block_sync_lds() {
  __asm__ volatile("s_waitcnt lgkmcnt(0)" ::: "memory");
  __builtin_amdgcn_s_barrier();
}

#define MFMA16(a, b, c) __builtin_amdgcn_mfma_f32_16x16x32_bf16((a), (b), (c), 0, 0, 0)

// D0: parallel dtype detector (fp32 adj words have zero low16; bf16 doesn't).
__global__ __launch_bounds__(256) void k_detect(const unsigned int* __restrict__ aw) {
  __shared__ int any;
  if (threadIdx.x == 0) any = 0;
  __syncthreads();
  const uint4 v = ((const uint4*)aw)[blockIdx.x * 256 + threadIdx.x];
  int loc = (int)((v.x & 0xFFFFu) | (v.y & 0xFFFFu) | (v.z & 0xFFFFu) | (v.w & 0xFFFFu));
  if (loc) atomicOr(&any, 1);
  __syncthreads();
  if (threadIdx.x == 0) g_anyArr[blockIdx.x] = any;
}

// S1: reduce detector flags -> g_mode; counting sort by seq_length descending.
__global__ __launch_bounds__(256) void k_sort(const int* __restrict__ seq) {
  __shared__ int hist[MAXDEG + 1];
  __shared__ int offs[MAXDEG + 1];
  const int tid = threadIdx.x;
  if (tid <= MAXDEG) hist[tid] = 0;
  __syncthreads();
  if (tid == 0) {
    int any = 0;
    for (int b = 0; b < 64; b++) any |= g_anyArr[b];
    g_mode = any ? 1 : 0;
  }
  for (int i = tid; i < N_NODES; i += 256)
    atomicAdd(&hist[min(max(seq[i], 0), MAXDEG)], 1);
  __syncthreads();
  if (tid == 0) {
    int run = 0;
    for (int L = MAXDEG; L >= 0; L--) { offs[L] = run; run += hist[L]; }
  }
  __syncthreads();
  for (int i = tid; i < N_NODES; i += 256) {
    int p = atomicAdd(&offs[min(max(seq[i], 0), MAXDEG)], 1);
    g_perm[p] = i;
  }
}

// K1: Wh = h @ W (fp64 acc), s1/s2 fp64 dots. Unchanged (proven).
__global__ __launch_bounds__(256) void k_wh(
    const void* __restrict__ h, const void* __restrict__ W, const void* __restrict__ a)
{
  const bool bf16 = (g_mode == 1);
  __shared__ float Ws[F_INN * F_OUTT];   // 64 KB
  const int tid = threadIdx.x;
  if (bf16) {
    const ushort4* Wu = (const ushort4*)W;
    for (int v = tid; v < F_INN * F_OUTT / 4; v += 256) {
      ushort4 u = Wu[v];
      ((float4*)Ws)[v] = make_float4(bf2f(u.x), bf2f(u.y), bf2f(u.z), bf2f(u.w));
    }
  } else {
    const float4* Wf = (const float4*)W;
    for (int v = tid; v < F_INN * F_OUTT / 4; v += 256) ((float4*)Ws)[v] = Wf[v];
  }
  __syncthreads();
  const int wave = tid >> 6, lane = tid & 63;
  const int row = blockIdx.x * 4 + wave;
  float hr0, hr1, hr2, hr3;
  if (bf16) {
    ushort4 v = ((const ushort4*)((const unsigned short*)h + row * F_INN))[lane];
    hr0 = bf2f(v.x); hr1 = bf2f(v.y); hr2 = bf2f(v.z); hr3 = bf2f(v.w);
  } else {
    float4 v = ((const float4*)((const float*)h + row * F_INN))[lane];
    hr0 = v.x; hr1 = v.y; hr2 = v.z; hr3 = v.w;
  }
  double acc = 0.0;
  #pragma unroll 8
  for (int l = 0; l < 64; l++) {
    float h0 = bcastf(hr0, l), h1 = bcastf(hr1, l);
    float h2 = bcastf(hr2, l), h3 = bcastf(hr3, l);
    acc += (double)h0 * (double)Ws[(l * 4 + 0) * F_OUTT + lane];
    acc += (double)h1 * (double)Ws[(l * 4 + 1) * F_OUTT + lane];
    acc += (double)h2 * (double)Ws[(l * 4 + 2) * F_OUTT + lane];
    acc += (double)h3 * (double)Ws[(l * 4 + 3) * F_OUTT + lane];
  }
  const float whv = (float)acc;
  g_Wh[row * F_OUTT + lane] = whv;
  float a1, a2;
  if (bf16) {
    a1 = bf2f(((const unsigned short*)a)[lane]);
    a2 = bf2f(((const unsigned short*)a)[F_OUTT + lane]);
  } else {
    a1 = ((const float*)a)[lane];
    a2 = ((const float*)a)[F_OUTT + lane];
  }
  double t1 = (double)whv * (double)a1;
  double t2 = (double)whv * (double)a2;
  #pragma unroll
  for (int off = 32; off > 0; off >>= 1) {
    t1 += __shfl_down(t1, off);
    t2 += __shfl_down(t2, off);
  }
  if (lane == 0) { g_s1[row] = (float)t1; g_s2[row] = (float)t2; }
}

// K2 v2 (r14): wave-per-row attention. r2 counters: k_att 65us at 8% HBM,
// VALUBusy 18%, ~44k cy latency per wave vs ~2k VALU -> serialization-bound
// (6 barriers, shared-atomic scan, non-pipelined fp64 gather, fp64 exp).
// New structure: 1 wave = 1 row, 4 rows/block. Zero barriers, zero atomics.
// - neighbor extraction: ballot + mbcnt prefix -> ordered-by-j list in LDS
// - softmax fp32 (__expf + rcp); rank compares fp32 att with tie -> smaller j
//   (same semantics as proven version / reference stable argsort)
// - Wh2 gather: 4 independent fp32 partial sums -> loads pipeline 4-deep
// - GEMV fp32; w_ih read from global (32KB, L1-resident; proven pattern)
// Order-critical s1/s2 remain fp64-produced by k_wh. fp32 changes touch
// magnitudes only: ~1e-5 error vs the 2e-3 bf16-dominated absmax budget.
__global__ __launch_bounds__(256) void k_att(
    const void* __restrict__ adj, const void* __restrict__ w_ih,
    const void* __restrict__ b_ih, const void* __restrict__ b_hh)
{
  const bool bf16 = (g_mode == 1);
  const int wv = threadIdx.x >> 6, lane = threadIdx.x & 63;
  const int i = blockIdx.x * 4 + wv;

  __shared__ int   s_nbr[4][MAXDEG];
  __shared__ float s_att[4][MAXDEG];
  __shared__ int   s_srt[4][MAXDEG];
  __shared__ float s_wh2[4][F_OUTT];
  int*   nbr  = s_nbr[wv];
  float* attp = s_att[wv];
  int*   srt  = s_srt[wv];
  float* wh2  = s_wh2[wv];

  // ---- Phase 1: ordered neighbor extraction (ballot-prefix, j ascending)
  int base = 0;
  if (bf16) {
    const uint4* ar = (const uint4*)((const unsigned short*)adj + (size_t)i * N_NODES);
    #pragma unroll
    for (int it = 0; it < 8; it++) {
      const uint4 v = ar[it * 64 + lane];
      unsigned word[4] = {v.x, v.y, v.z, v.w};
      bool nz[8];
      #pragma unroll
      for (int k = 0; k < 4; k++) {
        nz[2 * k]     = (word[k] & 0x0000FFFFu) != 0u;
        nz[2 * k + 1] = (word[k] & 0xFFFF0000u) != 0u;
      }
      int pre = 0, tot = 0;
      #pragma unroll
      for (int k = 0; k < 8; k++) {
        unsigned long long bl = __ballot(nz[k]);
        pre += mbcnt64(bl);
        tot += __popcll(bl);
      }
      int loc = 0;
      #pragma unroll
      for (int k = 0; k < 8; k++) {
        if (nz[k]) {
          int p = base + pre + loc;
          if (p < MAXDEG) nbr[p] = it * 512 + lane * 8 + k;
          loc++;
        }
      }
      base += tot;
    }
  } else {
    const float4* ar = (const float4*)((const float*)adj + (size_t)i * N_NODES);
    #pragma unroll
    for (int it = 0; it < 16; it++) {
      const float4 v = ar[it * 64 + lane];
      bool nz[4] = {v.x != 0.0f, v.y != 0.0f, v.z != 0.0f, v.w != 0.0f};
      int pre = 0, tot = 0;
      #pragma unroll
      for (int k = 0; k < 4; k++) {
        unsigned long long bl = __ballot(nz[k]);
        pre += mbcnt64(bl);
        tot += __popcll(bl);
      }
      int loc = 0;
      #pragma unroll
      for (int k = 0; k < 4; k++) {
        if (nz[k]) {
          int p = base + pre + loc;
          if (p < MAXDEG) nbr[p] = it * 256 + lane * 4 + k;
          loc++;
        }
      }
      base += tot;
    }
  }
  const int L = min(base, MAXDEG);
  // same-wave LDS write->read: DS ops execute in order per wave (no barrier
  // needed; different waves use disjoint LDS regions).

  // ---- Phase 2: softmax (fp32) + rank (att desc, tie j asc) + g_rev
  const int   jn  = (lane < L) ? nbr[lane] : 0;
  const float s2v = g_s2[jn];
  {
    float s = g_s1[i] + s2v;
    float e = (s > 0.0f) ? s : 0.2f * s;
    if (lane >= L) e = -3.0e38f;
    float m = e;
    #pragma unroll
    for (int off = 32; off > 0; off >>= 1) m = fmaxf(m, __shfl_xor(m, off));
    float p = (lane < L) ? __expf(e - m) : 0.0f;
    float ssum = p;
    #pragma unroll
    for (int off = 32; off > 0; off >>= 1) ssum += __shfl_xor(ssum, off);
    const float av = p * rcp_fast(ssum);
    attp[lane] = av;
    int rank = 0;
    for (int qq = 0; qq < L; qq++) {
      float aq = __shfl(av, qq);
      int   jq = __shfl(jn, qq);
      rank += (aq > av || (aq == av && jq < jn)) ? 1 : 0;
    }
    if (lane < L) srt[rank] = jn;
  }
  g_rev[i * MAXDEG + lane] = (lane < L) ? srt[L - 1 - lane] : 0;

  // ---- Phase 3: Wh2 row (fp32, 4 independent partials -> 4-deep pipeline)
  float a0 = 0.f, a1 = 0.f, a2 = 0.f, a3 = 0.f;
  int q = 0;
  for (; q + 4 <= L; q += 4) {
    const int j0 = nbr[q], j1 = nbr[q + 1], j2 = nbr[q + 2], j3 = nbr[q + 3];
    const float t0 = attp[q], t1 = attp[q + 1], t2 = attp[q + 2], t3 = attp[q + 3];
    a0 = fmaf(t0, g_Wh[(size_t)j0 * F_OUTT + lane], a0);
    a1 = fmaf(t1, g_Wh[(size_t)j1 * F_OUTT + lane], a1);
    a2 = fmaf(t2, g_Wh[(size_t)j2 * F_OUTT + lane], a2);
    a3 = fmaf(t3, g_Wh[(size_t)j3 * F_OUTT + lane], a3);
  }
  for (; q < L; q++) {
    const int j0 = nbr[q];
    a0 = fmaf(attp[q], g_Wh[(size_t)j0 * F_OUTT + lane], a0);
  }
  wh2[lane] = (a0 + a1) + (a2 + a3);

  // ---- Phase 4: GEMV gates for unit u=lane (4 w_ih rows) + bias -> g_GX
  float gx[4] = {0.f, 0.f, 0.f, 0.f};
  if (bf16) {
    #pragma unroll
    for (int g = 0; g < 4; g++) {
      const unsigned short* wr = (const unsigned short*)w_ih + (size_t)(g * 64 + lane) * F_OUTT;
      #pragma unroll
      for (int ch = 0; ch < 8; ch++) {
        bf16x8 vv = *(const bf16x8*)(wr + ch * 8);
        #pragma unroll
        for (int e2 = 0; e2 < 8; e2++)
          gx[g] = fmaf(bf2f((unsigned short)vv[e2]), wh2[ch * 8 + e2], gx[g]);
      }
      gx[g] += bf2f(((const unsigned short*)b_ih)[g * 64 + lane]) +
               bf2f(((const unsigned short*)b_hh)[g * 64 + lane]);
    }
  } else {
    #pragma unroll
    for (int g = 0; g < 4; g++) {
      const float* wr = (const float*)w_ih + (size_t)(g * 64 + lane) * F_OUTT;
      #pragma unroll
      for (int ch = 0; ch < 16; ch++) {
        float4 vv = *(const float4*)(wr + ch * 4);
        gx[g] = fmaf(vv.x, wh2[ch * 4 + 0], gx[g]);
        gx[g] = fmaf(vv.y, wh2[ch * 4 + 1], gx[g]);
        gx[g] = fmaf(vv.z, wh2[ch * 4 + 2], gx[g]);
        gx[g] = fmaf(vv.w, wh2[ch * 4 + 3], gx[g]);
      }
      gx[g] += ((const float*)b_ih)[g * 64 + lane] + ((const float*)b_hh)[g * 64 + lane];
    }
  }
  g_GX[(size_t)i * F_OUTT + lane] = make_float4(gx[0], gx[1], gx[2], gx[3]);
}

// K4-MFMA v10 (r13-proven): rcp-based gates, depth-4 gx ring, LDS idx.
__global__ __launch_bounds__(256, 1) void k_lstm_mfma(
    const void* __restrict__ w_hh, const int* __restrict__ seq,
    void* __restrict__ out)
{
  const bool bf16 = (g_mode == 1);
  __shared__ __align__(16) unsigned short lds_h[2][16 * 72];  // 4.5 KB dbuf
  __shared__ int lds_idx[16][MAXDEG];                         // 4 KB rev indices
  const int tid = threadIdx.x;
  const int w = tid >> 6, lane = tid & 63;
  const int q = lane >> 4, c = lane & 15;
  const int rb = blockIdx.x * 16;

  // Stage the block's 16 (permuted) rev-index rows into LDS, coalesced.
  for (int v = tid; v < 16 * MAXDEG; v += 256) {
    const int e = v >> 6, t0 = v & (MAXDEG - 1);
    const int row = g_perm[rb + e] & (N_NODES - 1);
    lds_idx[e][t0] = g_rev[row * MAXDEG + t0] & (N_NODES - 1);
  }

  const int Lmax = min(max(seq[g_perm[rb] & (N_NODES - 1)], 0), MAXDEG);
  int row_e[4], Ls_e[4];
  #pragma unroll
  for (int r = 0; r < 4; r++) {
    row_e[r] = g_perm[rb + q * 4 + r] & (N_NODES - 1);
    Ls_e[r]  = min(max(seq[row_e[r]], 0), MAXDEG);
  }
  const int d_unit = 16 * w + c;   // unit index 0..63 handled by this lane

  // B fragments (RNE bf16 of w_hh): col = unit 64g + 16w + c, k-chunk ch.
  bf16x8 Bhi[4][2];
  #pragma unroll
  for (int g = 0; g < 4; g++) {
    const int col = 64 * g + d_unit;
    #pragma unroll
    for (int ch = 0; ch < 2; ch++) {
      if (bf16) {
        Bhi[g][ch] = *(const bf16x8*)((const unsigned short*)w_hh + (size_t)col * 64 + ch * 32 + q * 8);
      } else {
        const float* wp = (const float*)w_hh + (size_t)col * 64 + ch * 32 + q * 8;
        float4 va = *(const float4*)wp, vb = *(const float4*)(wp + 4);
        bf16x8 f;
        f[0] = (short)f2bf(va.x); f[1] = (short)f2bf(va.y);
        f[2] = (short)f2bf(va.z); f[3] = (short)f2bf(va.w);
        f[4] = (short)f2bf(vb.x); f[5] = (short)f2bf(vb.y);
        f[6] = (short)f2bf(vb.z); f[7] = (short)f2bf(vb.w);
        Bhi[g][ch] = f;
      }
    }
  }

  __syncthreads();   // lds_idx visible to all waves

  // Depth-4 gx register ring: slot s holds step (group_base + s) data.
  float4 gxb[4][4];
  #pragma unroll
  for (int s = 0; s < 4; s++) {
    #pragma unroll
    for (int r = 0; r < 4; r++)
      gxb[s][r] = g_GX[lds_idx[q * 4 + r][s] * F_OUTT + d_unit];
  }
  // Pre-read indices for the first reload target (step 4).
  int idx_cur[4];
  #pragma unroll
  for (int r = 0; r < 4; r++) idx_cur[r] = lds_idx[q * 4 + r][4];

  bf16x8 h0 = zfrag(), h1 = zfrag();
  float cst[4] = {0.f, 0.f, 0.f, 0.f}, hst[4] = {0.f, 0.f, 0.f, 0.f};
  const int Lr = (Lmax + 3) & ~3;   // dead tail sub-steps are live-masked

  for (int t = 0; t < Lr; t += 4) {
    #pragma unroll
    for (int j = 0; j < 4; j++) {
      const int tt = t + j;
      // 8 MFMAs: 4 gates x 2-chain, C initialized from ring slot j.
      f32x4 acc[4];
      #pragma unroll
      for (int g = 0; g < 4; g++) {
        f32x4 a;
        a[0] = (g==0)?gxb[j][0].x:(g==1)?gxb[j][0].y:(g==2)?gxb[j][0].z:gxb[j][0].w;
        a[1] = (g==0)?gxb[j][1].x:(g==1)?gxb[j][1].y:(g==2)?gxb[j][1].z:gxb[j][1].w;
        a[2] = (g==0)?gxb[j][2].x:(g==1)?gxb[j][2].y:(g==2)?gxb[j][2].z:gxb[j][2].w;
        a[3] = (g==0)?gxb[j][3].x:(g==1)?gxb[j][3].y:(g==2)?gxb[j][3].z:gxb[j][3].w;
        a = MFMA16(h0, Bhi[g][0], a);
        a = MFMA16(h1, Bhi[g][1], a);
        acc[g] = a;
      }
      // Reload slot j with step tt+4 data (addresses already in registers).
      #pragma unroll
      for (int r = 0; r < 4; r++)
        gxb[j][r] = g_GX[idx_cur[r] * F_OUTT + d_unit];
      // Pre-read indices for the next sub-step's reload (step tt+5);
      // this ds_read drains at the barrier below, never on the fast path.
      {
        const int nt = min(tt + 5, MAXDEG - 1);
        #pragma unroll
        for (int r = 0; r < 4; r++) idx_cur[r] = lds_idx[q * 4 + r][nt];
      }
      // Gates + state update + bf16 h publish. rcp_fast-based sigm/tanh.
      unsigned short* lh = lds_h[j & 1];
      #pragma unroll
      for (int r = 0; r < 4; r++) {
        float ig = sigm(acc[0][r]);
        float fg = sigm(acc[1][r]);
        float gg = tanh_fast(acc[2][r]);
        float og = sigm(acc[3][r]);
        float cn = fg * cst[r] + ig * gg;
        float hn = og * tanh_fast(cn);
        bool live = (tt < Ls_e[r]);
        cst[r] = live ? cn : cst[r];
        hst[r] = live ? hn : hst[r];
        lh[(q * 4 + r) * 72 + d_unit] = f2bf(hst[r]);   // RNE bf16
      }
      block_sync_lds();   // lgkm-only: gx prefetches stay in flight
      // A-frags direct: row m=c, units k=8q..8q+7 (chunk0) / +32 (chunk1)
      {
        const unsigned short* lr_ = lds_h[j & 1] + c * 72;
        h0 = *(const bf16x8*)(lr_ + 8 * q);
        h1 = *(const bf16x8*)(lr_ + 32 + 8 * q);
      }
    }
  }
  #pragma unroll
  for (int r = 0; r < 4; r++) {
    if (bf16) ((__hip_bfloat16*)out)[row_e[r] * HID + d_unit] = __float2bfloat16(hst[r]);
    else      ((float*)out)[row_e[r] * HID + d_unit] = hst[r];
  }
}

extern "C" void kernel_launch(void* const* d_in, const int* in_sizes, int n_in,
                              void* d_out, int out_size, void* d_ws, size_t ws_size,
                              hipStream_t stream) {
  (void)in_sizes; (void)n_in; (void)out_size; (void)d_ws; (void)ws_size;
  const void* h    = d_in[0];
  const void* adj  = d_in[1];
  const int*  seq  = (const int*)d_in[2];
  const void* W    = d_in[3];
  const void* a    = d_in[4];
  const void* w_ih = d_in[5];
  const void* w_hh = d_in[6];
  const void* b_ih = d_in[7];
  const void* b_hh = d_in[8];

  k_detect   <<<64,           256, 0, stream>>>((const unsigned int*)adj);
  k_sort     <<<1,            256, 0, stream>>>(seq);
  k_wh       <<<N_NODES / 4,  256, 0, stream>>>(h, W, a);
  k_att      <<<N_NODES / 4,  256, 0, stream>>>(adj, w_ih, b_ih, b_hh);
  k_lstm_mfma<<<N_NODES / 16, 256, 0, stream>>>(w_hh, seq, d_out);
}

// Round 4
// 227.369 us; speedup vs baseline: 1.0268x; 1.0268x over previous
//
#include <hip/hip_runtime.h>
#include <hip/hip_bf16.h>
#include <math.h>

#define N_NODES 4096
#define F_INN   256
#define F_OUTT  64
#define HID     64
#define MAXDEG  64

typedef __attribute__((ext_vector_type(8))) short bf16x8;
typedef __attribute__((ext_vector_type(4))) float f32x4;

// Scratch in device globals (no ws_size dependence). Fully rewritten each call.
__device__ int    g_mode;                    // 0 = fp32 inputs, 1 = bf16 inputs
__device__ int    g_anyArr[64];              // per-block detector flags
__device__ float  g_Wh [N_NODES * F_OUTT];
__device__ float  g_s1 [N_NODES];
__device__ float  g_s2 [N_NODES];
__device__ int    g_rev[N_NODES * MAXDEG];
__device__ int    g_perm[N_NODES];
__device__ int    g_nbr[N_NODES * MAXDEG];   // ordered neighbor lists (j ascending)
__device__ int    g_cnt[N_NODES];            // neighbor counts
__device__ float4 g_GX [N_NODES * F_OUTT];   // per (node, unit): quad {i,f,g,o} + bias

__device__ __forceinline__ float bf2f(unsigned short u) {
  union { unsigned int i; float f; } v; v.i = ((unsigned int)u) << 16; return v.f;
}
__device__ __forceinline__ unsigned short f2bf(float f) {   // RNE
  union { __hip_bfloat16 b; unsigned short u; } v; v.b = __float2bfloat16(f); return v.u;
}

__device__ __forceinline__ float bcastf(float v, int l) {
  return __int_as_float(__builtin_amdgcn_readlane(__float_as_int(v), l));
}

// r13: raw v_rcp_f32 (1 inst, ~1e-7 rel err) instead of fp32 '/' (no
// fast-math -> IEEE div expansion of ~8-10 insts). Proven: 245 -> 227us.
__device__ __forceinline__ float rcp_fast(float x) { return __builtin_amdgcn_rcpf(x); }

__device__ __forceinline__ float sigm(float x) {
  return rcp_fast(1.f + __expf(-x));                   // mul,exp,add,rcp
}
__device__ __forceinline__ float tanh_fast(float x) {
  return fmaf(-2.f, rcp_fast(1.f + __expf(2.f * x)), 1.f);  // mul,exp,add,rcp,fma
}

// count of set bits in mask among lanes strictly below mine
__device__ __forceinline__ int mbcnt64(unsigned long long m) {
  return __builtin_amdgcn_mbcnt_hi((unsigned)(m >> 32),
         __builtin_amdgcn_mbcnt_lo((unsigned)(m & 0xFFFFFFFFull), 0));
}

__device__ __forceinline__ bf16x8 zfrag() {
  bf16x8 z;
  #pragma unroll
  for (int i = 0; i < 8; i++) z[i] = 0;
  return z;
}

// Lightweight block barrier for LDS-only exchange (r10-validated): orders ds
// ops but does not force a vmcnt drain of in-flight global prefetches.
__device__ __forceinline__ void block_sync_lds() {
  __asm__ volatile("s_waitcnt lgkmcnt(0)" ::: "memory");
  __builtin_amdgcn_s_barrier();
}

#define MFMA16(a, b, c) __builtin_amdgcn_mfma_f32_16x16x32_bf16((a), (b), (c), 0, 0, 0)

// D0: parallel dtype detector (fp32 adj words have zero low16; bf16 doesn't).
__global__ __launch_bounds__(256) void k_detect(const unsigned int* __restrict__ aw) {
  __shared__ int any;
  if (threadIdx.x == 0) any = 0;
  __syncthreads();
  const uint4 v = ((const uint4*)aw)[blockIdx.x * 256 + threadIdx.x];
  int loc = (int)((v.x & 0xFFFFu) | (v.y & 0xFFFFu) | (v.z & 0xFFFFu) | (v.w & 0xFFFFu));
  if (loc) atomicOr(&any, 1);
  __syncthreads();
  if (threadIdx.x == 0) g_anyArr[blockIdx.x] = any;
}

// S1: reduce detector flags -> g_mode; counting sort by seq_length descending.
__global__ __launch_bounds__(256) void k_sort(const int* __restrict__ seq) {
  __shared__ int hist[MAXDEG + 1];
  __shared__ int offs[MAXDEG + 1];
  const int tid = threadIdx.x;
  if (tid <= MAXDEG) hist[tid] = 0;
  __syncthreads();
  if (tid == 0) {
    int any = 0;
    for (int b = 0; b < 64; b++) any |= g_anyArr[b];
    g_mode = any ? 1 : 0;
  }
  for (int i = tid; i < N_NODES; i += 256)
    atomicAdd(&hist[min(max(seq[i], 0), MAXDEG)], 1);
  __syncthreads();
  if (tid == 0) {
    int run = 0;
    for (int L = MAXDEG; L >= 0; L--) { offs[L] = run; run += hist[L]; }
  }
  __syncthreads();
  for (int i = tid; i < N_NODES; i += 256) {
    int p = atomicAdd(&offs[min(max(seq[i], 0), MAXDEG)], 1);
    g_perm[p] = i;
  }
}

// K-SCAN (r15): block-per-row adj streaming + ordered neighbor extraction.
// r3 lesson: wave-per-row k_att had 4x fewer waves -> latency-bound (occ 17%,
// VALU 11%). The adj scan is the only mandatory 32MB HBM read; give it max
// parallelism (4096 blocks, 16k waves, low VGPR). Wave w scans contiguous
// quarter w of the row with the proven ballot+mbcnt ordered extraction;
// one LDS prefix over the 4 wave-counts stitches the global-ordered list.
__global__ __launch_bounds__(256) void k_scan(const void* __restrict__ adj) {
  const bool bf16 = (g_mode == 1);
  const int i = blockIdx.x;
  const int w = threadIdx.x >> 6, lane = threadIdx.x & 63;
  __shared__ int seg[4][MAXDEG];
  __shared__ int scnt[4];

  int base = 0;
  if (bf16) {
    const uint4* ar = (const uint4*)((const unsigned short*)adj + (size_t)i * N_NODES);
    #pragma unroll
    for (int it = 0; it < 2; it++) {
      const uint4 v = ar[w * 128 + it * 64 + lane];
      unsigned word[4] = {v.x, v.y, v.z, v.w};
      bool nz[8];
      #pragma unroll
      for (int k = 0; k < 4; k++) {
        nz[2 * k]     = (word[k] & 0x0000FFFFu) != 0u;
        nz[2 * k + 1] = (word[k] & 0xFFFF0000u) != 0u;
      }
      int pre = 0, tot = 0;
      #pragma unroll
      for (int k = 0; k < 8; k++) {
        unsigned long long bl = __ballot(nz[k]);
        pre += mbcnt64(bl);
        tot += __popcll(bl);
      }
      int loc = 0;
      #pragma unroll
      for (int k = 0; k < 8; k++) {
        if (nz[k]) {
          int p = base + pre + loc;
          if (p < MAXDEG) seg[w][p] = w * 1024 + it * 512 + lane * 8 + k;
          loc++;
        }
      }
      base += tot;
    }
  } else {
    const float4* ar = (const float4*)((const float*)adj + (size_t)i * N_NODES);
    #pragma unroll
    for (int it = 0; it < 4; it++) {
      const float4 v = ar[w * 256 + it * 64 + lane];
      bool nz[4] = {v.x != 0.0f, v.y != 0.0f, v.z != 0.0f, v.w != 0.0f};
      int pre = 0, tot = 0;
      #pragma unroll
      for (int k = 0; k < 4; k++) {
        unsigned long long bl = __ballot(nz[k]);
        pre += mbcnt64(bl);
        tot += __popcll(bl);
      }
      int loc = 0;
      #pragma unroll
      for (int k = 0; k < 4; k++) {
        if (nz[k]) {
          int p = base + pre + loc;
          if (p < MAXDEG) seg[w][p] = w * 1024 + it * 256 + lane * 4 + k;
          loc++;
        }
      }
      base += tot;
    }
  }
  if (lane == 0) scnt[w] = base;
  __syncthreads();
  int off = 0;
  #pragma unroll
  for (int u = 0; u < 4; u++) off += (u < w) ? scnt[u] : 0;
  const int cw = min(scnt[w], MAXDEG);
  if (lane < cw) {
    const int p = off + lane;
    if (p < MAXDEG) g_nbr[i * MAXDEG + p] = seg[w][lane];
  }
  if (threadIdx.x == 0)
    g_cnt[i] = min(scnt[0] + scnt[1] + scnt[2] + scnt[3], MAXDEG);
}

// K1: Wh = h @ W (fp64 acc), s1/s2 fp64 dots. Unchanged (proven).
__global__ __launch_bounds__(256) void k_wh(
    const void* __restrict__ h, const void* __restrict__ W, const void* __restrict__ a)
{
  const bool bf16 = (g_mode == 1);
  __shared__ float Ws[F_INN * F_OUTT];   // 64 KB
  const int tid = threadIdx.x;
  if (bf16) {
    const ushort4* Wu = (const ushort4*)W;
    for (int v = tid; v < F_INN * F_OUTT / 4; v += 256) {
      ushort4 u = Wu[v];
      ((float4*)Ws)[v] = make_float4(bf2f(u.x), bf2f(u.y), bf2f(u.z), bf2f(u.w));
    }
  } else {
    const float4* Wf = (const float4*)W;
    for (int v = tid; v < F_INN * F_OUTT / 4; v += 256) ((float4*)Ws)[v] = Wf[v];
  }
  __syncthreads();
  const int wave = tid >> 6, lane = tid & 63;
  const int row = blockIdx.x * 4 + wave;
  float hr0, hr1, hr2, hr3;
  if (bf16) {
    ushort4 v = ((const ushort4*)((const unsigned short*)h + row * F_INN))[lane];
    hr0 = bf2f(v.x); hr1 = bf2f(v.y); hr2 = bf2f(v.z); hr3 = bf2f(v.w);
  } else {
    float4 v = ((const float4*)((const float*)h + row * F_INN))[lane];
    hr0 = v.x; hr1 = v.y; hr2 = v.z; hr3 = v.w;
  }
  double acc = 0.0;
  #pragma unroll 8
  for (int l = 0; l < 64; l++) {
    float h0 = bcastf(hr0, l), h1 = bcastf(hr1, l);
    float h2 = bcastf(hr2, l), h3 = bcastf(hr3, l);
    acc += (double)h0 * (double)Ws[(l * 4 + 0) * F_OUTT + lane];
    acc += (double)h1 * (double)Ws[(l * 4 + 1) * F_OUTT + lane];
    acc += (double)h2 * (double)Ws[(l * 4 + 2) * F_OUTT + lane];
    acc += (double)h3 * (double)Ws[(l * 4 + 3) * F_OUTT + lane];
  }
  const float whv = (float)acc;
  g_Wh[row * F_OUTT + lane] = whv;
  float a1, a2;
  if (bf16) {
    a1 = bf2f(((const unsigned short*)a)[lane]);
    a2 = bf2f(((const unsigned short*)a)[F_OUTT + lane]);
  } else {
    a1 = ((const float*)a)[lane];
    a2 = ((const float*)a)[F_OUTT + lane];
  }
  double t1 = (double)whv * (double)a1;
  double t2 = (double)whv * (double)a2;
  #pragma unroll
  for (int off = 32; off > 0; off >>= 1) {
    t1 += __shfl_down(t1, off);
    t2 += __shfl_down(t2, off);
  }
  if (lane == 0) { g_s1[row] = (float)t1; g_s2[row] = (float)t2; }
}

// K2 v3 (r15): wave-per-row tail (softmax/rank/gather/GEMV), adj scan moved
// to k_scan. Phase 1 is now one coalesced neighbor-list load -> serial chain
// ~3x shorter, VGPR lower, latency hideable at 16 waves/CU.
// Proven phases 2-4 from r14 kept byte-identical in logic.
__global__ __launch_bounds__(256) void k_att2(
    const void* __restrict__ w_ih,
    const void* __restrict__ b_ih, const void* __restrict__ b_hh)
{
  const bool bf16 = (g_mode == 1);
  const int wv = threadIdx.x >> 6, lane = threadIdx.x & 63;
  const int i = blockIdx.x * 4 + wv;

  __shared__ int   s_nbr[4][MAXDEG];
  __shared__ float s_att[4][MAXDEG];
  __shared__ int   s_srt[4][MAXDEG];
  __shared__ float s_wh2[4][F_OUTT];
  int*   nbr  = s_nbr[wv];
  float* attp = s_att[wv];
  int*   srt  = s_srt[wv];
  float* wh2  = s_wh2[wv];

  // ---- Phase 1: load ordered neighbor list (one coalesced read)
  const int L = min(g_cnt[i], MAXDEG);
  int jn = 0;
  if (lane < L) jn = g_nbr[i * MAXDEG + lane] & (N_NODES - 1);
  nbr[lane] = jn;

  // ---- Phase 2: softmax (fp32) + rank (att desc, tie j asc) + g_rev
  const float s2v = g_s2[jn];
  float av;
  {
    float s = g_s1[i] + s2v;
    float e = (s > 0.0f) ? s : 0.2f * s;
    if (lane >= L) e = -3.0e38f;
    float m = e;
    #pragma unroll
    for (int off = 32; off > 0; off >>= 1) m = fmaxf(m, __shfl_xor(m, off));
    float p = (lane < L) ? __expf(e - m) : 0.0f;
    float ssum = p;
    #pragma unroll
    for (int off = 32; off > 0; off >>= 1) ssum += __shfl_xor(ssum, off);
    av = p * rcp_fast(ssum);
    attp[lane] = av;
    int rank = 0;
    for (int qq = 0; qq < L; qq++) {
      float aq = __shfl(av, qq);
      int   jq = __shfl(jn, qq);
      rank += (aq > av || (aq == av && jq < jn)) ? 1 : 0;
    }
    if (lane < L) srt[rank] = jn;
  }
  g_rev[i * MAXDEG + lane] = (lane < L) ? srt[L - 1 - lane] : 0;

  // ---- Phase 3: Wh2 row (fp32, 4 independent partials -> 4-deep pipeline)
  float a0 = 0.f, a1 = 0.f, a2 = 0.f, a3 = 0.f;
  int q = 0;
  for (; q + 4 <= L; q += 4) {
    const int j0 = nbr[q], j1 = nbr[q + 1], j2 = nbr[q + 2], j3 = nbr[q + 3];
    const float t0 = attp[q], t1 = attp[q + 1], t2 = attp[q + 2], t3 = attp[q + 3];
    a0 = fmaf(t0, g_Wh[(size_t)j0 * F_OUTT + lane], a0);
    a1 = fmaf(t1, g_Wh[(size_t)j1 * F_OUTT + lane], a1);
    a2 = fmaf(t2, g_Wh[(size_t)j2 * F_OUTT + lane], a2);
    a3 = fmaf(t3, g_Wh[(size_t)j3 * F_OUTT + lane], a3);
  }
  for (; q < L; q++) {
    const int j0 = nbr[q];
    a0 = fmaf(attp[q], g_Wh[(size_t)j0 * F_OUTT + lane], a0);
  }
  wh2[lane] = (a0 + a1) + (a2 + a3);

  // ---- Phase 4: GEMV gates for unit u=lane (4 w_ih rows) + bias -> g_GX
  float gx[4] = {0.f, 0.f, 0.f, 0.f};
  if (bf16) {
    #pragma unroll
    for (int g = 0; g < 4; g++) {
      const unsigned short* wr = (const unsigned short*)w_ih + (size_t)(g * 64 + lane) * F_OUTT;
      #pragma unroll
      for (int ch = 0; ch < 8; ch++) {
        bf16x8 vv = *(const bf16x8*)(wr + ch * 8);
        #pragma unroll
        for (int e2 = 0; e2 < 8; e2++)
          gx[g] = fmaf(bf2f((unsigned short)vv[e2]), wh2[ch * 8 + e2], gx[g]);
      }
      gx[g] += bf2f(((const unsigned short*)b_ih)[g * 64 + lane]) +
               bf2f(((const unsigned short*)b_hh)[g * 64 + lane]);
    }
  } else {
    #pragma unroll
    for (int g = 0; g < 4; g++) {
      const float* wr = (const float*)w_ih + (size_t)(g * 64 + lane) * F_OUTT;
      #pragma unroll
      for (int ch = 0; ch < 16; ch++) {
        float4 vv = *(const float4*)(wr + ch * 4);
        gx[g] = fmaf(vv.x, wh2[ch * 4 + 0], gx[g]);
        gx[g] = fmaf(vv.y, wh2[ch * 4 + 1], gx[g]);
        gx[g] = fmaf(vv.z, wh2[ch * 4 + 2], gx[g]);
        gx[g] = fmaf(vv.w, wh2[ch * 4 + 3], gx[g]);
      }
      gx[g] += ((const float*)b_ih)[g * 64 + lane] + ((const float*)b_hh)[g * 64 + lane];
    }
  }
  g_GX[(size_t)i * F_OUTT + lane] = make_float4(gx[0], gx[1], gx[2], gx[3]);
}

// K4-MFMA v10 (r13-proven): rcp-based gates, depth-4 gx ring, LDS idx.
__global__ __launch_bounds__(256, 1) void k_lstm_mfma(
    const void* __restrict__ w_hh, const int* __restrict__ seq,
    void* __restrict__ out)
{
  const bool bf16 = (g_mode == 1);
  __shared__ __align__(16) unsigned short lds_h[2][16 * 72];  // 4.5 KB dbuf
  __shared__ int lds_idx[16][MAXDEG];                         // 4 KB rev indices
  const int tid = threadIdx.x;
  const int w = tid >> 6, lane = tid & 63;
  const int q = lane >> 4, c = lane & 15;
  const int rb = blockIdx.x * 16;

  // Stage the block's 16 (permuted) rev-index rows into LDS, coalesced.
  for (int v = tid; v < 16 * MAXDEG; v += 256) {
    const int e = v >> 6, t0 = v & (MAXDEG - 1);
    const int row = g_perm[rb + e] & (N_NODES - 1);
    lds_idx[e][t0] = g_rev[row * MAXDEG + t0] & (N_NODES - 1);
  }

  const int Lmax = min(max(seq[g_perm[rb] & (N_NODES - 1)], 0), MAXDEG);
  int row_e[4], Ls_e[4];
  #pragma unroll
  for (int r = 0; r < 4; r++) {
    row_e[r] = g_perm[rb + q * 4 + r] & (N_NODES - 1);
    Ls_e[r]  = min(max(seq[row_e[r]], 0), MAXDEG);
  }
  const int d_unit = 16 * w + c;   // unit index 0..63 handled by this lane

  // B fragments (RNE bf16 of w_hh): col = unit 64g + 16w + c, k-chunk ch.
  bf16x8 Bhi[4][2];
  #pragma unroll
  for (int g = 0; g < 4; g++) {
    const int col = 64 * g + d_unit;
    #pragma unroll
    for (int ch = 0; ch < 2; ch++) {
      if (bf16) {
        Bhi[g][ch] = *(const bf16x8*)((const unsigned short*)w_hh + (size_t)col * 64 + ch * 32 + q * 8);
      } else {
        const float* wp = (const float*)w_hh + (size_t)col * 64 + ch * 32 + q * 8;
        float4 va = *(const float4*)wp, vb = *(const float4*)(wp + 4);
        bf16x8 f;
        f[0] = (short)f2bf(va.x); f[1] = (short)f2bf(va.y);
        f[2] = (short)f2bf(va.z); f[3] = (short)f2bf(va.w);
        f[4] = (short)f2bf(vb.x); f[5] = (short)f2bf(vb.y);
        f[6] = (short)f2bf(vb.z); f[7] = (short)f2bf(vb.w);
        Bhi[g][ch] = f;
      }
    }
  }

  __syncthreads();   // lds_idx visible to all waves

  // Depth-4 gx register ring: slot s holds step (group_base + s) data.
  float4 gxb[4][4];
  #pragma unroll
  for (int s = 0; s < 4; s++) {
    #pragma unroll
    for (int r = 0; r < 4; r++)
      gxb[s][r] = g_GX[lds_idx[q * 4 + r][s] * F_OUTT + d_unit];
  }
  // Pre-read indices for the first reload target (step 4).
  int idx_cur[4];
  #pragma unroll
  for (int r = 0; r < 4; r++) idx_cur[r] = lds_idx[q * 4 + r][4];

  bf16x8 h0 = zfrag(), h1 = zfrag();
  float cst[4] = {0.f, 0.f, 0.f, 0.f}, hst[4] = {0.f, 0.f, 0.f, 0.f};
  const int Lr = (Lmax + 3) & ~3;   // dead tail sub-steps are live-masked

  for (int t = 0; t < Lr; t += 4) {
    #pragma unroll
    for (int j = 0; j < 4; j++) {
      const int tt = t + j;
      // 8 MFMAs: 4 gates x 2-chain, C initialized from ring slot j.
      f32x4 acc[4];
      #pragma unroll
      for (int g = 0; g < 4; g++) {
        f32x4 a;
        a[0] = (g==0)?gxb[j][0].x:(g==1)?gxb[j][0].y:(g==2)?gxb[j][0].z:gxb[j][0].w;
        a[1] = (g==0)?gxb[j][1].x:(g==1)?gxb[j][1].y:(g==2)?gxb[j][1].z:gxb[j][1].w;
        a[2] = (g==0)?gxb[j][2].x:(g==1)?gxb[j][2].y:(g==2)?gxb[j][2].z:gxb[j][2].w;
        a[3] = (g==0)?gxb[j][3].x:(g==1)?gxb[j][3].y:(g==2)?gxb[j][3].z:gxb[j][3].w;
        a = MFMA16(h0, Bhi[g][0], a);
        a = MFMA16(h1, Bhi[g][1], a);
        acc[g] = a;
      }
      // Reload slot j with step tt+4 data (addresses already in registers).
      #pragma unroll
      for (int r = 0; r < 4; r++)
        gxb[j][r] = g_GX[idx_cur[r] * F_OUTT + d_unit];
      // Pre-read indices for the next sub-step's reload (step tt+5);
      // this ds_read drains at the barrier below, never on the fast path.
      {
        const int nt = min(tt + 5, MAXDEG - 1);
        #pragma unroll
        for (int r = 0; r < 4; r++) idx_cur[r] = lds_idx[q * 4 + r][nt];
      }
      // Gates + state update + bf16 h publish. rcp_fast-based sigm/tanh.
      unsigned short* lh = lds_h[j & 1];
      #pragma unroll
      for (int r = 0; r < 4; r++) {
        float ig = sigm(acc[0][r]);
        float fg = sigm(acc[1][r]);
        float gg = tanh_fast(acc[2][r]);
        float og = sigm(acc[3][r]);
        float cn = fg * cst[r] + ig * gg;
        float hn = og * tanh_fast(cn);
        bool live = (tt < Ls_e[r]);
        cst[r] = live ? cn : cst[r];
        hst[r] = live ? hn : hst[r];
        lh[(q * 4 + r) * 72 + d_unit] = f2bf(hst[r]);   // RNE bf16
      }
      block_sync_lds();   // lgkm-only: gx prefetches stay in flight
      // A-frags direct: row m=c, units k=8q..8q+7 (chunk0) / +32 (chunk1)
      {
        const unsigned short* lr_ = lds_h[j & 1] + c * 72;
        h0 = *(const bf16x8*)(lr_ + 8 * q);
        h1 = *(const bf16x8*)(lr_ + 32 + 8 * q);
      }
    }
  }
  #pragma unroll
  for (int r = 0; r < 4; r++) {
    if (bf16) ((__hip_bfloat16*)out)[row_e[r] * HID + d_unit] = __float2bfloat16(hst[r]);
    else      ((float*)out)[row_e[r] * HID + d_unit] = hst[r];
  }
}

extern "C" void kernel_launch(void* const* d_in, const int* in_sizes, int n_in,
                              void* d_out, int out_size, void* d_ws, size_t ws_size,
                              hipStream_t stream) {
  (void)in_sizes; (void)n_in; (void)out_size; (void)d_ws; (void)ws_size;
  const void* h    = d_in[0];
  const void* adj  = d_in[1];
  const int*  seq  = (const int*)d_in[2];
  const void* W    = d_in[3];
  const void* a    = d_in[4];
  const void* w_ih = d_in[5];
  const void* w_hh = d_in[6];
  const void* b_ih = d_in[7];
  const void* b_hh = d_in[8];

  k_detect   <<<64,           256, 0, stream>>>((const unsigned int*)adj);
  k_sort     <<<1,            256, 0, stream>>>(seq);
  k_scan     <<<N_NODES,      256, 0, stream>>>(adj);
  k_wh       <<<N_NODES / 4,  256, 0, stream>>>(h, W, a);
  k_att2     <<<N_NODES / 4,  256, 0, stream>>>(w_ih, b_ih, b_hh);
  k_lstm_mfma<<<N_NODES / 16, 256, 0, stream>>>(w_hh, seq, d_out);
}